// Round 6
// baseline (365.966 us; speedup 1.0000x reference)
//
#include <hip/hip_runtime.h>
#include <math.h>

#define DD 128
#define HH 256
#define WD 256
#define HWS (HH*WD)
#define VOLS ((size_t)DD*HWS)
#define DC 8           // slices per wave-tile -> 16 d-chunks
#define NT 256
#define FINF (__builtin_inff())

__device__ __forceinline__ float min3f(float a, float b, float c) {
  return fminf(fminf(a, b), c);   // fuses to v_min3_f32
}
__device__ __forceinline__ float max3f(float a, float b, float c) {
  return fmaxf(fmaxf(a, b), c);   // fuses to v_max3_f32
}

#define MIN3V(d,a,b,c) do{ (d).x=min3f((a).x,(b).x,(c).x); (d).y=min3f((a).y,(b).y,(c).y); \
                           (d).z=min3f((a).z,(b).z,(c).z); (d).w=min3f((a).w,(b).w,(c).w);}while(0)
#define MAX3V(d,a,b,c) do{ (d).x=max3f((a).x,(b).x,(c).x); (d).y=max3f((a).y,(b).y,(c).y); \
                           (d).z=max3f((a).z,(b).z,(c).z); (d).w=max3f((a).w,(b).w,(c).w);}while(0)
#define SET4(d,val)    do{ (d).x=(val); (d).y=(val); (d).z=(val); (d).w=(val);}while(0)

// One pipeline step for staged slice zS = (SARG).
// All macro-local names are z*/vv-prefixed to avoid shadowing caller vars
// (R4 failed on `const int S = (S);` self-init).
// Writes m2(zS) into M2WR (parity array of zS), mx(zS-1) into MXWR (parity
// of zS-1). Emits skel output for slice zo = zS-2 when zoOut.
#define STEP(SARG, M2WR, MXWR) do {                                           \
    const int  zS    = (SARG);                                                \
    const bool zsOK  = (zS >= 0 && zS < DD);                                  \
    const bool zeOK  = (zS >= 1 && zS <= DD);                                 \
    const int  zo    = zS - 2;                                                \
    const bool zoOut = (zS >= d0 + 2);                                        \
    float4 vr0, vr1, vr2, vr3, vr4, vr5, vr6, vr7;                            \
    float4 ic0, ic1, ic2, ic3, ot0, ot1, ot2, ot3;                            \
    /* ---- issue all global loads up front (16 coalesced float4/lane) ---- */\
    if (zsOK) {                                                               \
      const float* sb = imgL + (size_t)zS * HWS;                              \
      if (hOK0) vr0 = *(const float4*)(sb - 2*WD); else SET4(vr0, FINF);      \
      if (hOK1) vr1 = *(const float4*)(sb - 1*WD); else SET4(vr1, FINF);      \
      vr2 = *(const float4*)(sb);                                             \
      vr3 = *(const float4*)(sb + 1*WD);                                      \
      vr4 = *(const float4*)(sb + 2*WD);                                      \
      vr5 = *(const float4*)(sb + 3*WD);                                      \
      if (hOK6) vr6 = *(const float4*)(sb + 4*WD); else SET4(vr6, FINF);      \
      if (hOK7) vr7 = *(const float4*)(sb + 5*WD); else SET4(vr7, FINF);      \
    } else {                                                                  \
      SET4(vr0,FINF); SET4(vr1,FINF); SET4(vr2,FINF); SET4(vr3,FINF);         \
      SET4(vr4,FINF); SET4(vr5,FINF); SET4(vr6,FINF); SET4(vr7,FINF);         \
    }                                                                         \
    if (zoOut) {                                                              \
      const float* ib = imgL + (size_t)zo * HWS;                              \
      const float* ob = othL + (size_t)zo * HWS;                              \
      ic0 = *(const float4*)(ib);          ic1 = *(const float4*)(ib + WD);   \
      ic2 = *(const float4*)(ib + 2*WD);   ic3 = *(const float4*)(ib + 3*WD); \
      ot0 = *(const float4*)(ob);          ot1 = *(const float4*)(ob + WD);   \
      ot2 = *(const float4*)(ob + 2*WD);   ot3 = *(const float4*)(ob + 3*WD); \
    }                                                                         \
    float4 mw_p2, mw_p1, opn_p2, opn_p1;                                      \
    SET4(mw_p2,FINF); SET4(mw_p1,FINF); SET4(opn_p2,-FINF); SET4(opn_p1,-FINF);\
    _Pragma("unroll")                                                         \
    for (int rr = 0; rr < 8; ++rr) {                                          \
      float4 vv = (rr==0)?vr0:(rr==1)?vr1:(rr==2)?vr2:(rr==3)?vr3:            \
                  (rr==4)?vr4:(rr==5)?vr5:(rr==6)?vr6:vr7;                    \
      float lw = __shfl_up(vv.w, 1);   lw = (lane == 0)  ? FINF : lw;         \
      float rx = __shfl_down(vv.x, 1); rx = (lane == 63) ? FINF : rx;         \
      float4 mw;                                                              \
      mw.x = min3f(lw, vv.x, vv.y);   mw.y = min3f(vv.x, vv.y, vv.z);         \
      mw.z = min3f(vv.y, vv.z, vv.w); mw.w = min3f(vv.z, vv.w, rx);           \
      if (rr >= 2) {                                                          \
        const int ri = rr - 2;                                                \
        float4 m2c; MIN3V(m2c, mw_p2, mw_p1, mw);                             \
        float4 er;  MIN3V(er, m2c, m2_0[ri], m2_1[ri]);                       \
        M2WR[ri] = m2c;                                                       \
        if (!(zeOK && ehOK[ri])) SET4(er, -FINF);                             \
        float elw = __shfl_up(er.w, 1);   elw = (lane == 0)  ? -FINF : elw;   \
        float erx = __shfl_down(er.x, 1); erx = (lane == 63) ? -FINF : erx;   \
        float4 mx;                                                            \
        mx.x = max3f(elw, er.x, er.y);  mx.y = max3f(er.x, er.y, er.z);       \
        mx.z = max3f(er.y, er.z, er.w); mx.w = max3f(er.z, er.w, erx);        \
        float4 opn; MAX3V(opn, mx, mx_0[ri], mx_1[ri]);                       \
        MXWR[ri] = mx;                                                        \
        if (rr >= 4) {                                                        \
          float4 opened; MAX3V(opened, opn_p2, opn_p1, opn);                  \
          if (zoOut) {                                                        \
            float4 icv = (rr==4)?ic0:(rr==5)?ic1:(rr==6)?ic2:ic3;             \
            float4 otv = (rr==4)?ot0:(rr==5)?ot1:(rr==6)?ot2:ot3;             \
            float4 sk;                                                        \
            sk.x = fmaxf(icv.x - opened.x, 0.f);                              \
            sk.y = fmaxf(icv.y - opened.y, 0.f);                              \
            sk.z = fmaxf(icv.z - opened.z, 0.f);                              \
            sk.w = fmaxf(icv.w - opened.w, 0.f);                              \
            accN4.x += sk.x * otv.x; accN4.y += sk.y * otv.y;                 \
            accN4.z += sk.z * otv.z; accN4.w += sk.w * otv.w;                 \
            accD4.x += sk.x; accD4.y += sk.y;                                 \
            accD4.z += sk.z; accD4.w += sk.w;                                 \
          }                                                                   \
        }                                                                     \
        opn_p2 = opn_p1; opn_p1 = opn;                                        \
      }                                                                       \
      mw_p2 = mw_p1; mw_p1 = mw;                                              \
    }                                                                         \
  } while (0)

__global__ __launch_bounds__(NT, 4) void skel_reduce_kernel(
    const float* __restrict__ y_pred, const float* __restrict__ y_true,
    double* __restrict__ acc)
{
  __shared__ float red[2][4];

  const int tid  = threadIdx.x;
  const int wid  = tid >> 6;
  const int lane = tid & 63;
  const int gwv  = blockIdx.x * 4 + wid;     // 0..4095
  const int ht = gwv & 63;                   // 64 h-tiles of 4 rows
  const int dt = (gwv >> 6) & 15;            // 16 d-chunks of 8 slices
  const int v  = gwv >> 10;                  // role*2 + b (block-uniform)
  const int role = v >> 1, b = v & 1;

  const float* img = (role == 0 ? y_pred : y_true) + (size_t)b * VOLS;
  const float* oth = (role == 0 ? y_true : y_pred) + (size_t)b * VOLS;

  const int h0 = ht * 4, d0 = dt * DC;
  const float* imgL = img + (size_t)h0 * WD + 4 * lane;
  const float* othL = oth + (size_t)h0 * WD + 4 * lane;

  // h-border validity (wave-uniform)
  const bool hOK0 = (h0 - 2 >= 0), hOK1 = (h0 - 1 >= 0);
  const bool hOK6 = (h0 + 4 < HH), hOK7 = (h0 + 5 < HH);
  bool ehOK[6];
  #pragma unroll
  for (int i = 0; i < 6; ++i) ehOK[i] = ((unsigned)(h0 + i - 1) < HH);

  // D-direction ping-pong state: m2_0 = even slices, m2_1 = odd (same for mx)
  float4 m2_0[6], m2_1[6], mx_0[6], mx_1[6];
  #pragma unroll
  for (int i = 0; i < 6; ++i) {
    SET4(m2_0[i], FINF);  SET4(m2_1[i], FINF);
    SET4(mx_0[i], -FINF); SET4(mx_1[i], -FINF);
  }
  float4 accN4, accD4; SET4(accN4, 0.f); SET4(accD4, 0.f);

  // d0 is even, so slice parity is compile-time within the 2x-unrolled loop.
  for (int SS = d0 - 2; SS < d0 + DC + 2; SS += 2) {
    STEP(SS,     m2_0, mx_1);
    STEP(SS + 1, m2_1, mx_0);
  }

  float accN = accN4.x + accN4.y + accN4.z + accN4.w;
  float accD = accD4.x + accD4.y + accD4.z + accD4.w;
  #pragma unroll
  for (int off = 32; off > 0; off >>= 1) {
    accN += __shfl_down(accN, off);
    accD += __shfl_down(accD, off);
  }
  if (lane == 0) { red[0][wid] = accN; red[1][wid] = accD; }
  __syncthreads();
  if (tid == 0) {
    float n  = red[0][0] + red[0][1] + red[0][2] + red[0][3];
    float dn = red[1][0] + red[1][1] + red[1][2] + red[1][3];
    atomicAdd(&acc[v * 2 + 0], (double)n);
    atomicAdd(&acc[v * 2 + 1], (double)dn);
  }
}

__global__ void finalize_kernel(const double* __restrict__ acc,
                                float* __restrict__ out)
{
  const double smooth = 1e-5;
  double cl[2];
  for (int b = 0; b < 2; ++b) {
    double tprec = acc[(0 * 2 + b) * 2 + 0] / (acc[(0 * 2 + b) * 2 + 1] + smooth);
    double tsens = acc[(1 * 2 + b) * 2 + 0] / (acc[(1 * 2 + b) * 2 + 1] + smooth);
    cl[b] = 2.0 * tprec * tsens / (tprec + tsens + smooth);
  }
  out[0] = (float)(1.0 - 0.5 * (cl[0] + cl[1]));
}

extern "C" void kernel_launch(void* const* d_in, const int* in_sizes, int n_in,
                              void* d_out, int out_size, void* d_ws, size_t ws_size,
                              hipStream_t stream) {
  const float* y_pred = (const float*)d_in[0];
  const float* y_true = (const float*)d_in[1];
  double* acc = (double*)d_ws;
  hipMemsetAsync(d_ws, 0, 8 * sizeof(double), stream);
  // 4096 waves: 4 role-vols x 16 d-chunks x 64 h-tiles -> 1024 blocks x 4 waves
  skel_reduce_kernel<<<dim3(1024), dim3(NT), 0, stream>>>(y_pred, y_true, acc);
  finalize_kernel<<<dim3(1), dim3(1), 0, stream>>>(acc, (float*)d_out);
}

// Round 7
// 88.645 us; speedup vs baseline: 4.1285x; 4.1285x over previous
//
#include <hip/hip_runtime.h>
#include <math.h>

#define DD 128
#define HH 256
#define WD 256
#define HWS (HH*WD)
#define VOLS ((size_t)DD*HWS)
#define DC 8           // slices per wave-tile -> 16 d-chunks
#define NT 256
#define FINF (__builtin_inff())

__device__ __forceinline__ float min3f(float a, float b, float c) {
  return fminf(fminf(a, b), c);   // fuses to v_min3_f32
}
__device__ __forceinline__ float max3f(float a, float b, float c) {
  return fmaxf(fmaxf(a, b), c);   // fuses to v_max3_f32
}

#define MIN3V(d,a,b,c) do{ (d).x=min3f((a).x,(b).x,(c).x); (d).y=min3f((a).y,(b).y,(c).y); \
                           (d).z=min3f((a).z,(b).z,(c).z); (d).w=min3f((a).w,(b).w,(c).w);}while(0)
#define MAX3V(d,a,b,c) do{ (d).x=max3f((a).x,(b).x,(c).x); (d).y=max3f((a).y,(b).y,(c).y); \
                           (d).z=max3f((a).z,(b).z,(c).z); (d).w=max3f((a).w,(b).w,(c).w);}while(0)
#define SET4(d,val)    do{ (d).x=(val); (d).y=(val); (d).z=(val); (d).w=(val);}while(0)

// One pipeline step for staged slice zS = (SARG).
// All macro-local names are z*/vv-prefixed to avoid shadowing caller vars
// (R4 failed on `const int S = (S);` self-init).
// Writes m2(zS) into M2WR (parity array of zS), mx(zS-1) into MXWR (parity
// of zS-1). Emits skel output for slice zo = zS-2 when zoOut.
#define STEP(SARG, M2WR, MXWR) do {                                           \
    const int  zS    = (SARG);                                                \
    const bool zsOK  = (zS >= 0 && zS < DD);                                  \
    const bool zeOK  = (zS >= 1 && zS <= DD);                                 \
    const int  zo    = zS - 2;                                                \
    const bool zoOut = (zS >= d0 + 2);                                        \
    float4 vr0, vr1, vr2, vr3, vr4, vr5, vr6, vr7;                            \
    float4 ic0, ic1, ic2, ic3, ot0, ot1, ot2, ot3;                            \
    /* ---- issue all global loads up front (16 coalesced float4/lane) ---- */\
    if (zsOK) {                                                               \
      const float* sb = imgL + (size_t)zS * HWS;                              \
      if (hOK0) vr0 = *(const float4*)(sb - 2*WD); else SET4(vr0, FINF);      \
      if (hOK1) vr1 = *(const float4*)(sb - 1*WD); else SET4(vr1, FINF);      \
      vr2 = *(const float4*)(sb);                                             \
      vr3 = *(const float4*)(sb + 1*WD);                                      \
      vr4 = *(const float4*)(sb + 2*WD);                                      \
      vr5 = *(const float4*)(sb + 3*WD);                                      \
      if (hOK6) vr6 = *(const float4*)(sb + 4*WD); else SET4(vr6, FINF);      \
      if (hOK7) vr7 = *(const float4*)(sb + 5*WD); else SET4(vr7, FINF);      \
    } else {                                                                  \
      SET4(vr0,FINF); SET4(vr1,FINF); SET4(vr2,FINF); SET4(vr3,FINF);         \
      SET4(vr4,FINF); SET4(vr5,FINF); SET4(vr6,FINF); SET4(vr7,FINF);         \
    }                                                                         \
    if (zoOut) {                                                              \
      const float* ib = imgL + (size_t)zo * HWS;                              \
      const float* ob = othL + (size_t)zo * HWS;                              \
      ic0 = *(const float4*)(ib);          ic1 = *(const float4*)(ib + WD);   \
      ic2 = *(const float4*)(ib + 2*WD);   ic3 = *(const float4*)(ib + 3*WD); \
      ot0 = *(const float4*)(ob);          ot1 = *(const float4*)(ob + WD);   \
      ot2 = *(const float4*)(ob + 2*WD);   ot3 = *(const float4*)(ob + 3*WD); \
    }                                                                         \
    float4 mw_p2, mw_p1, opn_p2, opn_p1;                                      \
    SET4(mw_p2,FINF); SET4(mw_p1,FINF); SET4(opn_p2,-FINF); SET4(opn_p1,-FINF);\
    _Pragma("unroll")                                                         \
    for (int rr = 0; rr < 8; ++rr) {                                          \
      float4 vv = (rr==0)?vr0:(rr==1)?vr1:(rr==2)?vr2:(rr==3)?vr3:            \
                  (rr==4)?vr4:(rr==5)?vr5:(rr==6)?vr6:vr7;                    \
      float lw = __shfl_up(vv.w, 1);   lw = (lane == 0)  ? FINF : lw;         \
      float rx = __shfl_down(vv.x, 1); rx = (lane == 63) ? FINF : rx;         \
      float4 mw;                                                              \
      mw.x = min3f(lw, vv.x, vv.y);   mw.y = min3f(vv.x, vv.y, vv.z);         \
      mw.z = min3f(vv.y, vv.z, vv.w); mw.w = min3f(vv.z, vv.w, rx);           \
      if (rr >= 2) {                                                          \
        const int ri = rr - 2;                                                \
        float4 m2c; MIN3V(m2c, mw_p2, mw_p1, mw);                             \
        float4 er;  MIN3V(er, m2c, m2_0[ri], m2_1[ri]);                       \
        M2WR[ri] = m2c;                                                       \
        if (!(zeOK && ehOK[ri])) SET4(er, -FINF);                             \
        float elw = __shfl_up(er.w, 1);   elw = (lane == 0)  ? -FINF : elw;   \
        float erx = __shfl_down(er.x, 1); erx = (lane == 63) ? -FINF : erx;   \
        float4 mx;                                                            \
        mx.x = max3f(elw, er.x, er.y);  mx.y = max3f(er.x, er.y, er.z);       \
        mx.z = max3f(er.y, er.z, er.w); mx.w = max3f(er.z, er.w, erx);        \
        float4 opn; MAX3V(opn, mx, mx_0[ri], mx_1[ri]);                       \
        MXWR[ri] = mx;                                                        \
        if (rr >= 4) {                                                        \
          float4 opened; MAX3V(opened, opn_p2, opn_p1, opn);                  \
          if (zoOut) {                                                        \
            float4 icv = (rr==4)?ic0:(rr==5)?ic1:(rr==6)?ic2:ic3;             \
            float4 otv = (rr==4)?ot0:(rr==5)?ot1:(rr==6)?ot2:ot3;             \
            float4 sk;                                                        \
            sk.x = fmaxf(icv.x - opened.x, 0.f);                              \
            sk.y = fmaxf(icv.y - opened.y, 0.f);                              \
            sk.z = fmaxf(icv.z - opened.z, 0.f);                              \
            sk.w = fmaxf(icv.w - opened.w, 0.f);                              \
            accN4.x += sk.x * otv.x; accN4.y += sk.y * otv.y;                 \
            accN4.z += sk.z * otv.z; accN4.w += sk.w * otv.w;                 \
            accD4.x += sk.x; accD4.y += sk.y;                                 \
            accD4.z += sk.z; accD4.w += sk.w;                                 \
          }                                                                   \
        }                                                                     \
        opn_p2 = opn_p1; opn_p1 = opn;                                        \
      }                                                                       \
      mw_p2 = mw_p1; mw_p1 = mw;                                              \
    }                                                                         \
  } while (0)

// NOTE: (NT,2) not (NT,4): the 4-hint clamped VGPR to 64 and spilled ~530 MB
// to scratch (R6: 366us, WRITE_SIZE 674MB). At the natural ~120 VGPR (<=128)
// the HW already schedules 4 waves/SIMD; the grid provides the TLP.
__global__ __launch_bounds__(NT, 2) void skel_reduce_kernel(
    const float* __restrict__ y_pred, const float* __restrict__ y_true,
    double* __restrict__ acc)
{
  __shared__ float red[2][4];

  const int tid  = threadIdx.x;
  const int wid  = tid >> 6;
  const int lane = tid & 63;
  const int gwv  = blockIdx.x * 4 + wid;     // 0..4095
  const int ht = gwv & 63;                   // 64 h-tiles of 4 rows
  const int dt = (gwv >> 6) & 15;            // 16 d-chunks of 8 slices
  const int v  = gwv >> 10;                  // role*2 + b (block-uniform)
  const int role = v >> 1, b = v & 1;

  const float* img = (role == 0 ? y_pred : y_true) + (size_t)b * VOLS;
  const float* oth = (role == 0 ? y_true : y_pred) + (size_t)b * VOLS;

  const int h0 = ht * 4, d0 = dt * DC;
  const float* imgL = img + (size_t)h0 * WD + 4 * lane;
  const float* othL = oth + (size_t)h0 * WD + 4 * lane;

  // h-border validity (wave-uniform)
  const bool hOK0 = (h0 - 2 >= 0), hOK1 = (h0 - 1 >= 0);
  const bool hOK6 = (h0 + 4 < HH), hOK7 = (h0 + 5 < HH);
  bool ehOK[6];
  #pragma unroll
  for (int i = 0; i < 6; ++i) ehOK[i] = ((unsigned)(h0 + i - 1) < HH);

  // D-direction ping-pong state: m2_0 = even slices, m2_1 = odd (same for mx)
  float4 m2_0[6], m2_1[6], mx_0[6], mx_1[6];
  #pragma unroll
  for (int i = 0; i < 6; ++i) {
    SET4(m2_0[i], FINF);  SET4(m2_1[i], FINF);
    SET4(mx_0[i], -FINF); SET4(mx_1[i], -FINF);
  }
  float4 accN4, accD4; SET4(accN4, 0.f); SET4(accD4, 0.f);

  // d0 is even, so slice parity is compile-time within the 2x-unrolled loop.
  for (int SS = d0 - 2; SS < d0 + DC + 2; SS += 2) {
    STEP(SS,     m2_0, mx_1);
    STEP(SS + 1, m2_1, mx_0);
  }

  float accN = accN4.x + accN4.y + accN4.z + accN4.w;
  float accD = accD4.x + accD4.y + accD4.z + accD4.w;
  #pragma unroll
  for (int off = 32; off > 0; off >>= 1) {
    accN += __shfl_down(accN, off);
    accD += __shfl_down(accD, off);
  }
  if (lane == 0) { red[0][wid] = accN; red[1][wid] = accD; }
  __syncthreads();
  if (tid == 0) {
    float n  = red[0][0] + red[0][1] + red[0][2] + red[0][3];
    float dn = red[1][0] + red[1][1] + red[1][2] + red[1][3];
    atomicAdd(&acc[v * 2 + 0], (double)n);
    atomicAdd(&acc[v * 2 + 1], (double)dn);
  }
}

__global__ void finalize_kernel(const double* __restrict__ acc,
                                float* __restrict__ out)
{
  const double smooth = 1e-5;
  double cl[2];
  for (int b = 0; b < 2; ++b) {
    double tprec = acc[(0 * 2 + b) * 2 + 0] / (acc[(0 * 2 + b) * 2 + 1] + smooth);
    double tsens = acc[(1 * 2 + b) * 2 + 0] / (acc[(1 * 2 + b) * 2 + 1] + smooth);
    cl[b] = 2.0 * tprec * tsens / (tprec + tsens + smooth);
  }
  out[0] = (float)(1.0 - 0.5 * (cl[0] + cl[1]));
}

extern "C" void kernel_launch(void* const* d_in, const int* in_sizes, int n_in,
                              void* d_out, int out_size, void* d_ws, size_t ws_size,
                              hipStream_t stream) {
  const float* y_pred = (const float*)d_in[0];
  const float* y_true = (const float*)d_in[1];
  double* acc = (double*)d_ws;
  hipMemsetAsync(d_ws, 0, 8 * sizeof(double), stream);
  // 4096 waves: 4 role-vols x 16 d-chunks x 64 h-tiles -> 1024 blocks x 4 waves
  skel_reduce_kernel<<<dim3(1024), dim3(NT), 0, stream>>>(y_pred, y_true, acc);
  finalize_kernel<<<dim3(1), dim3(1), 0, stream>>>(acc, (float*)d_out);
}

// Round 8
// 84.325 us; speedup vs baseline: 4.3399x; 1.0512x over previous
//
#include <hip/hip_runtime.h>
#include <math.h>

#define DD 128
#define HH 256
#define WD 256
#define HWS (HH*WD)
#define VOLS ((size_t)DD*HWS)
#define DC 8           // slices per wave-tile -> 16 d-chunks
#define NT 256
#define NWG 1024       // grid blocks (must be %8==0 for the XCD swizzle)
#define FINF (__builtin_inff())

__device__ __forceinline__ float min3f(float a, float b, float c) {
  return fminf(fminf(a, b), c);   // fuses to v_min3_f32
}
__device__ __forceinline__ float max3f(float a, float b, float c) {
  return fmaxf(fmaxf(a, b), c);   // fuses to v_max3_f32
}

#define MIN3V(d,a,b,c) do{ (d).x=min3f((a).x,(b).x,(c).x); (d).y=min3f((a).y,(b).y,(c).y); \
                           (d).z=min3f((a).z,(b).z,(c).z); (d).w=min3f((a).w,(b).w,(c).w);}while(0)
#define MAX3V(d,a,b,c) do{ (d).x=max3f((a).x,(b).x,(c).x); (d).y=max3f((a).y,(b).y,(c).y); \
                           (d).z=max3f((a).z,(b).z,(c).z); (d).w=max3f((a).w,(b).w,(c).w);}while(0)
#define SET4(d,val)    do{ (d).x=(val); (d).y=(val); (d).z=(val); (d).w=(val);}while(0)

// One pipeline step for staged slice zS = (SARG).
// All macro-local names are z*/vv-prefixed to avoid shadowing caller vars
// (R4 failed on `const int S = (S);` self-init).
// Writes m2(zS) into M2WR (parity array of zS), mx(zS-1) into MXWR (parity
// of zS-1). Emits skel output for slice zo = zS-2 when zoOut.
#define STEP(SARG, M2WR, MXWR) do {                                           \
    const int  zS    = (SARG);                                                \
    const bool zsOK  = (zS >= 0 && zS < DD);                                  \
    const bool zeOK  = (zS >= 1 && zS <= DD);                                 \
    const int  zo    = zS - 2;                                                \
    const bool zoOut = (zS >= d0 + 2);                                        \
    float4 vr0, vr1, vr2, vr3, vr4, vr5, vr6, vr7;                            \
    float4 ic0, ic1, ic2, ic3, ot0, ot1, ot2, ot3;                            \
    /* ---- issue all global loads up front (16 coalesced float4/lane) ---- */\
    if (zsOK) {                                                               \
      const float* sb = imgL + (size_t)zS * HWS;                              \
      if (hOK0) vr0 = *(const float4*)(sb - 2*WD); else SET4(vr0, FINF);      \
      if (hOK1) vr1 = *(const float4*)(sb - 1*WD); else SET4(vr1, FINF);      \
      vr2 = *(const float4*)(sb);                                             \
      vr3 = *(const float4*)(sb + 1*WD);                                      \
      vr4 = *(const float4*)(sb + 2*WD);                                      \
      vr5 = *(const float4*)(sb + 3*WD);                                      \
      if (hOK6) vr6 = *(const float4*)(sb + 4*WD); else SET4(vr6, FINF);      \
      if (hOK7) vr7 = *(const float4*)(sb + 5*WD); else SET4(vr7, FINF);      \
    } else {                                                                  \
      SET4(vr0,FINF); SET4(vr1,FINF); SET4(vr2,FINF); SET4(vr3,FINF);         \
      SET4(vr4,FINF); SET4(vr5,FINF); SET4(vr6,FINF); SET4(vr7,FINF);         \
    }                                                                         \
    if (zoOut) {                                                              \
      const float* ib = imgL + (size_t)zo * HWS;                              \
      const float* ob = othL + (size_t)zo * HWS;                              \
      ic0 = *(const float4*)(ib);          ic1 = *(const float4*)(ib + WD);   \
      ic2 = *(const float4*)(ib + 2*WD);   ic3 = *(const float4*)(ib + 3*WD); \
      ot0 = *(const float4*)(ob);          ot1 = *(const float4*)(ob + WD);   \
      ot2 = *(const float4*)(ob + 2*WD);   ot3 = *(const float4*)(ob + 3*WD); \
    }                                                                         \
    float4 mw_p2, mw_p1, opn_p2, opn_p1;                                      \
    SET4(mw_p2,FINF); SET4(mw_p1,FINF); SET4(opn_p2,-FINF); SET4(opn_p1,-FINF);\
    _Pragma("unroll")                                                         \
    for (int rr = 0; rr < 8; ++rr) {                                          \
      float4 vv = (rr==0)?vr0:(rr==1)?vr1:(rr==2)?vr2:(rr==3)?vr3:            \
                  (rr==4)?vr4:(rr==5)?vr5:(rr==6)?vr6:vr7;                    \
      float lw = __shfl_up(vv.w, 1);   lw = (lane == 0)  ? FINF : lw;         \
      float rx = __shfl_down(vv.x, 1); rx = (lane == 63) ? FINF : rx;         \
      float4 mw;                                                              \
      mw.x = min3f(lw, vv.x, vv.y);   mw.y = min3f(vv.x, vv.y, vv.z);         \
      mw.z = min3f(vv.y, vv.z, vv.w); mw.w = min3f(vv.z, vv.w, rx);           \
      if (rr >= 2) {                                                          \
        const int ri = rr - 2;                                                \
        float4 m2c; MIN3V(m2c, mw_p2, mw_p1, mw);                             \
        float4 er;  MIN3V(er, m2c, m2_0[ri], m2_1[ri]);                       \
        M2WR[ri] = m2c;                                                       \
        if (!(zeOK && ehOK[ri])) SET4(er, -FINF);                             \
        float elw = __shfl_up(er.w, 1);   elw = (lane == 0)  ? -FINF : elw;   \
        float erx = __shfl_down(er.x, 1); erx = (lane == 63) ? -FINF : erx;   \
        float4 mx;                                                            \
        mx.x = max3f(elw, er.x, er.y);  mx.y = max3f(er.x, er.y, er.z);       \
        mx.z = max3f(er.y, er.z, er.w); mx.w = max3f(er.z, er.w, erx);        \
        float4 opn; MAX3V(opn, mx, mx_0[ri], mx_1[ri]);                       \
        MXWR[ri] = mx;                                                        \
        if (rr >= 4) {                                                        \
          float4 opened; MAX3V(opened, opn_p2, opn_p1, opn);                  \
          if (zoOut) {                                                        \
            float4 icv = (rr==4)?ic0:(rr==5)?ic1:(rr==6)?ic2:ic3;             \
            float4 otv = (rr==4)?ot0:(rr==5)?ot1:(rr==6)?ot2:ot3;             \
            float4 sk;                                                        \
            sk.x = fmaxf(icv.x - opened.x, 0.f);                              \
            sk.y = fmaxf(icv.y - opened.y, 0.f);                              \
            sk.z = fmaxf(icv.z - opened.z, 0.f);                              \
            sk.w = fmaxf(icv.w - opened.w, 0.f);                              \
            accN4.x += sk.x * otv.x; accN4.y += sk.y * otv.y;                 \
            accN4.z += sk.z * otv.z; accN4.w += sk.w * otv.w;                 \
            accD4.x += sk.x; accD4.y += sk.y;                                 \
            accD4.z += sk.z; accD4.w += sk.w;                                 \
          }                                                                   \
        }                                                                     \
        opn_p2 = opn_p1; opn_p1 = opn;                                        \
      }                                                                       \
      mw_p2 = mw_p1; mw_p1 = mw;                                              \
    }                                                                         \
  } while (0)

// NO second __launch_bounds__ arg: evidence across R2/R3/R5/R6/R7 shows the
// waves-per-eu attr acts as an occupancy CAP (2 -> ~6 waves/CU, 4 -> ~12-14,
// none -> ~15) and at 4 it also clamped VGPR to 64 causing 530MB of spill.
// VGPR ~120 naturally fits 4 waves/SIMD; let HW reach it.
__global__ __launch_bounds__(NT) void skel_reduce_kernel(
    const float* __restrict__ y_pred, const float* __restrict__ y_true,
    double* __restrict__ acc)
{
  __shared__ float red[2][4];

  const int tid  = threadIdx.x;
  const int wid  = tid >> 6;
  const int lane = tid & 63;
  // Bijective XCD swizzle (1024 blocks, 8 XCDs): XCD x (= bid%8) gets the
  // contiguous swizzled range [x*128, (x+1)*128) -> each XCD owns one
  // contiguous (volume, D-half, all-H) region; halo/ic/ot re-reads stay
  // XCD-local in L2.
  const int bidsw = (blockIdx.x & 7) * (NWG / 8) + (blockIdx.x >> 3);
  const int gwv  = bidsw * 4 + wid;          // 0..4095
  const int ht = gwv & 63;                   // 64 h-tiles of 4 rows
  const int dt = (gwv >> 6) & 15;            // 16 d-chunks of 8 slices
  const int v  = gwv >> 10;                  // role*2 + b (wave-uniform)
  const int role = v >> 1, b = v & 1;

  const float* img = (role == 0 ? y_pred : y_true) + (size_t)b * VOLS;
  const float* oth = (role == 0 ? y_true : y_pred) + (size_t)b * VOLS;

  const int h0 = ht * 4, d0 = dt * DC;
  const float* imgL = img + (size_t)h0 * WD + 4 * lane;
  const float* othL = oth + (size_t)h0 * WD + 4 * lane;

  // h-border validity (wave-uniform)
  const bool hOK0 = (h0 - 2 >= 0), hOK1 = (h0 - 1 >= 0);
  const bool hOK6 = (h0 + 4 < HH), hOK7 = (h0 + 5 < HH);
  bool ehOK[6];
  #pragma unroll
  for (int i = 0; i < 6; ++i) ehOK[i] = ((unsigned)(h0 + i - 1) < HH);

  // D-direction ping-pong state: m2_0 = even slices, m2_1 = odd (same for mx)
  float4 m2_0[6], m2_1[6], mx_0[6], mx_1[6];
  #pragma unroll
  for (int i = 0; i < 6; ++i) {
    SET4(m2_0[i], FINF);  SET4(m2_1[i], FINF);
    SET4(mx_0[i], -FINF); SET4(mx_1[i], -FINF);
  }
  float4 accN4, accD4; SET4(accN4, 0.f); SET4(accD4, 0.f);

  // d0 is even, so slice parity is compile-time within the 2x-unrolled loop.
  for (int SS = d0 - 2; SS < d0 + DC + 2; SS += 2) {
    STEP(SS,     m2_0, mx_1);
    STEP(SS + 1, m2_1, mx_0);
  }

  float accN = accN4.x + accN4.y + accN4.z + accN4.w;
  float accD = accD4.x + accD4.y + accD4.z + accD4.w;
  #pragma unroll
  for (int off = 32; off > 0; off >>= 1) {
    accN += __shfl_down(accN, off);
    accD += __shfl_down(accD, off);
  }
  if (lane == 0) { red[0][wid] = accN; red[1][wid] = accD; }
  __syncthreads();
  if (tid == 0) {
    // v is wave-uniform but can differ across the block's 4 waves only at
    // volume boundaries (gwv>>10); waves of one block always share v since
    // bidsw*4..bidsw*4+3 stay within one 1024-wave volume range.
    float n  = red[0][0] + red[0][1] + red[0][2] + red[0][3];
    float dn = red[1][0] + red[1][1] + red[1][2] + red[1][3];
    atomicAdd(&acc[v * 2 + 0], (double)n);
    atomicAdd(&acc[v * 2 + 1], (double)dn);
  }
}

__global__ void finalize_kernel(const double* __restrict__ acc,
                                float* __restrict__ out)
{
  const double smooth = 1e-5;
  double cl[2];
  for (int b = 0; b < 2; ++b) {
    double tprec = acc[(0 * 2 + b) * 2 + 0] / (acc[(0 * 2 + b) * 2 + 1] + smooth);
    double tsens = acc[(1 * 2 + b) * 2 + 0] / (acc[(1 * 2 + b) * 2 + 1] + smooth);
    cl[b] = 2.0 * tprec * tsens / (tprec + tsens + smooth);
  }
  out[0] = (float)(1.0 - 0.5 * (cl[0] + cl[1]));
}

extern "C" void kernel_launch(void* const* d_in, const int* in_sizes, int n_in,
                              void* d_out, int out_size, void* d_ws, size_t ws_size,
                              hipStream_t stream) {
  const float* y_pred = (const float*)d_in[0];
  const float* y_true = (const float*)d_in[1];
  double* acc = (double*)d_ws;
  hipMemsetAsync(d_ws, 0, 8 * sizeof(double), stream);
  // 4096 waves: 4 role-vols x 16 d-chunks x 64 h-tiles -> 1024 blocks x 4 waves
  skel_reduce_kernel<<<dim3(NWG), dim3(NT), 0, stream>>>(y_pred, y_true, acc);
  finalize_kernel<<<dim3(1), dim3(1), 0, stream>>>(acc, (float*)d_out);
}

// Round 9
// 75.479 us; speedup vs baseline: 4.8486x; 1.1172x over previous
//
#include <hip/hip_runtime.h>
#include <math.h>

#define DD 128
#define HH 256
#define WD 256
#define HWS (HH*WD)
#define VOLS ((size_t)DD*HWS)
#define DC 16          // slices per wave-tile -> 8 d-chunks (R5 best config)
#define NT 256
#define NWG 512        // blocks; %8==0 for XCD swizzle
#define FINF (__builtin_inff())

__device__ __forceinline__ float min3f(float a, float b, float c) {
  return fminf(fminf(a, b), c);   // fuses to v_min3_f32
}
__device__ __forceinline__ float max3f(float a, float b, float c) {
  return fmaxf(fmaxf(a, b), c);   // fuses to v_max3_f32
}

#define MIN3V(d,a,b,c) do{ (d).x=min3f((a).x,(b).x,(c).x); (d).y=min3f((a).y,(b).y,(c).y); \
                           (d).z=min3f((a).z,(b).z,(c).z); (d).w=min3f((a).w,(b).w,(c).w);}while(0)
#define MAX3V(d,a,b,c) do{ (d).x=max3f((a).x,(b).x,(c).x); (d).y=max3f((a).y,(b).y,(c).y); \
                           (d).z=max3f((a).z,(b).z,(c).z); (d).w=max3f((a).w,(b).w,(c).w);}while(0)
#define SET4(d,val)    do{ (d).x=(val); (d).y=(val); (d).z=(val); (d).w=(val);}while(0)

// Issue the 8 stage-row loads for slice (SLARG) into N0..N7 (INF-filled when
// the slice is outside [0,DD) or beyond the last compute slice).
#define PRESTAGE(SLARG, N0,N1,N2,N3,N4,N5,N6,N7) do {                         \
    const int zps = (SLARG);                                                  \
    if (zps >= 0 && zps < DD && zps <= d0 + DC + 1) {                         \
      const float* zpb = imgL + (size_t)zps * HWS;                            \
      if (hOK0) N0 = *(const float4*)(zpb - 2*WD); else SET4(N0, FINF);       \
      if (hOK1) N1 = *(const float4*)(zpb - 1*WD); else SET4(N1, FINF);       \
      N2 = *(const float4*)(zpb);                                             \
      N3 = *(const float4*)(zpb + 1*WD);                                      \
      N4 = *(const float4*)(zpb + 2*WD);                                      \
      N5 = *(const float4*)(zpb + 3*WD);                                      \
      if (hOK6) N6 = *(const float4*)(zpb + 4*WD); else SET4(N6, FINF);       \
      if (hOK7) N7 = *(const float4*)(zpb + 5*WD); else SET4(N7, FINF);       \
    } else {                                                                  \
      SET4(N0,FINF); SET4(N1,FINF); SET4(N2,FINF); SET4(N3,FINF);             \
      SET4(N4,FINF); SET4(N5,FINF); SET4(N6,FINF); SET4(N7,FINF);             \
    }                                                                         \
  } while (0)

// One pipeline step for slice zS: C0..C7 hold slice zS's rows (loaded by the
// PREVIOUS step's PRESTAGE -> global latency is off the critical path).
// Issue order matters for counted vmcnt: ic/ot FIRST (consumed this step,
// waiting on them must not drain the younger prefetch), then PRESTAGE(zS+1).
// All macro locals z*-prefixed (R4 lesson: no self-init shadowing).
#define STEPC(SARG, C0,C1,C2,C3,C4,C5,C6,C7, N0,N1,N2,N3,N4,N5,N6,N7, M2WR, MXWR) do { \
    const int  zS    = (SARG);                                                \
    const bool zeOK  = (zS >= 1 && zS <= DD);                                 \
    const int  zo    = zS - 2;                                                \
    const bool zoOut = (zS >= d0 + 2);                                        \
    float4 ic0, ic1, ic2, ic3, ot0, ot1, ot2, ot3;                            \
    if (zoOut) {                                                              \
      const float* ib = imgL + (size_t)zo * HWS;                              \
      const float* ob = othL + (size_t)zo * HWS;                              \
      ic0 = *(const float4*)(ib);          ic1 = *(const float4*)(ib + WD);   \
      ic2 = *(const float4*)(ib + 2*WD);   ic3 = *(const float4*)(ib + 3*WD); \
      ot0 = *(const float4*)(ob);          ot1 = *(const float4*)(ob + WD);   \
      ot2 = *(const float4*)(ob + 2*WD);   ot3 = *(const float4*)(ob + 3*WD); \
    }                                                                         \
    PRESTAGE(zS + 1, N0,N1,N2,N3,N4,N5,N6,N7);                                \
    float4 mw_p2, mw_p1, opn_p2, opn_p1;                                      \
    SET4(mw_p2,FINF); SET4(mw_p1,FINF); SET4(opn_p2,-FINF); SET4(opn_p1,-FINF);\
    _Pragma("unroll")                                                         \
    for (int rr = 0; rr < 8; ++rr) {                                          \
      float4 vv = (rr==0)?C0:(rr==1)?C1:(rr==2)?C2:(rr==3)?C3:                \
                  (rr==4)?C4:(rr==5)?C5:(rr==6)?C6:C7;                        \
      float lw = __shfl_up(vv.w, 1);   lw = (lane == 0)  ? FINF : lw;         \
      float rx = __shfl_down(vv.x, 1); rx = (lane == 63) ? FINF : rx;         \
      float4 mw;                                                              \
      mw.x = min3f(lw, vv.x, vv.y);   mw.y = min3f(vv.x, vv.y, vv.z);         \
      mw.z = min3f(vv.y, vv.z, vv.w); mw.w = min3f(vv.z, vv.w, rx);           \
      if (rr >= 2) {                                                          \
        const int ri = rr - 2;                                                \
        float4 m2c; MIN3V(m2c, mw_p2, mw_p1, mw);                             \
        float4 er;  MIN3V(er, m2c, m2_0[ri], m2_1[ri]);                       \
        M2WR[ri] = m2c;                                                       \
        if (!(zeOK && ehOK[ri])) SET4(er, -FINF);                             \
        float elw = __shfl_up(er.w, 1);   elw = (lane == 0)  ? -FINF : elw;   \
        float erx = __shfl_down(er.x, 1); erx = (lane == 63) ? -FINF : erx;   \
        float4 mx;                                                            \
        mx.x = max3f(elw, er.x, er.y);  mx.y = max3f(er.x, er.y, er.z);       \
        mx.z = max3f(er.y, er.z, er.w); mx.w = max3f(er.z, er.w, erx);        \
        float4 opn; MAX3V(opn, mx, mx_0[ri], mx_1[ri]);                       \
        MXWR[ri] = mx;                                                        \
        if (rr >= 4) {                                                        \
          float4 opened; MAX3V(opened, opn_p2, opn_p1, opn);                  \
          if (zoOut) {                                                        \
            float4 icv = (rr==4)?ic0:(rr==5)?ic1:(rr==6)?ic2:ic3;             \
            float4 otv = (rr==4)?ot0:(rr==5)?ot1:(rr==6)?ot2:ot3;             \
            float4 sk;                                                        \
            sk.x = fmaxf(icv.x - opened.x, 0.f);                              \
            sk.y = fmaxf(icv.y - opened.y, 0.f);                              \
            sk.z = fmaxf(icv.z - opened.z, 0.f);                              \
            sk.w = fmaxf(icv.w - opened.w, 0.f);                              \
            accN4.x += sk.x * otv.x; accN4.y += sk.y * otv.y;                 \
            accN4.z += sk.z * otv.z; accN4.w += sk.w * otv.w;                 \
            accD4.x += sk.x; accD4.y += sk.y;                                 \
            accD4.z += sk.z; accD4.w += sk.w;                                 \
          }                                                                   \
        }                                                                     \
        opn_p2 = opn_p1; opn_p1 = opn;                                        \
      }                                                                       \
      mw_p2 = mw_p1; mw_p1 = mw;                                              \
    }                                                                         \
  } while (0)

// No waves-per-eu hint: natural allocation, no clamp, no spill (R6 lesson).
__global__ __launch_bounds__(NT) void skel_reduce_kernel(
    const float* __restrict__ y_pred, const float* __restrict__ y_true,
    double* __restrict__ acc)
{
  __shared__ float red[2][4];

  const int tid  = threadIdx.x;
  const int wid  = tid >> 6;
  const int lane = tid & 63;
  // Bijective XCD swizzle (512 blocks, 8 XCDs): each XCD owns a contiguous
  // (volume, D-half) region -> halo/ic/ot re-reads stay XCD-local in L2.
  const int bidsw = (blockIdx.x & 7) * (NWG / 8) + (blockIdx.x >> 3);
  const int gwv  = bidsw * 4 + wid;          // 0..2047
  const int ht = gwv & 63;                   // 64 h-tiles of 4 rows
  const int dt = (gwv >> 6) & 7;             // 8 d-chunks of 16 slices
  const int v  = gwv >> 9;                   // role*2 + b (block-uniform)
  const int role = v >> 1, b = v & 1;

  const float* img = (role == 0 ? y_pred : y_true) + (size_t)b * VOLS;
  const float* oth = (role == 0 ? y_true : y_pred) + (size_t)b * VOLS;

  const int h0 = ht * 4, d0 = dt * DC;
  const float* imgL = img + (size_t)h0 * WD + 4 * lane;
  const float* othL = oth + (size_t)h0 * WD + 4 * lane;

  // h-border validity (wave-uniform)
  const bool hOK0 = (h0 - 2 >= 0), hOK1 = (h0 - 1 >= 0);
  const bool hOK6 = (h0 + 4 < HH), hOK7 = (h0 + 5 < HH);
  bool ehOK[6];
  #pragma unroll
  for (int i = 0; i < 6; ++i) ehOK[i] = ((unsigned)(h0 + i - 1) < HH);

  // D-direction ping-pong state: m2_0 = even slices, m2_1 = odd (same for mx)
  float4 m2_0[6], m2_1[6], mx_0[6], mx_1[6];
  #pragma unroll
  for (int i = 0; i < 6; ++i) {
    SET4(m2_0[i], FINF);  SET4(m2_1[i], FINF);
    SET4(mx_0[i], -FINF); SET4(mx_1[i], -FINF);
  }
  float4 accN4, accD4; SET4(accN4, 0.f); SET4(accD4, 0.f);

  // Double-buffered slice rows: A holds even-step slice, B odd-step slice.
  float4 a0,a1,a2,a3,a4,a5,a6,a7, b0,b1,b2,b3,b4,b5,b6,b7;

  // Prologue: prefetch slice d0-2 into A (consumed by the first step).
  PRESTAGE(d0 - 2, a0,a1,a2,a3,a4,a5,a6,a7);

  // 20 steps; d0 even -> slice parity and buffer role are compile-time.
  for (int SS = d0 - 2; SS < d0 + DC + 2; SS += 2) {
    STEPC(SS,     a0,a1,a2,a3,a4,a5,a6,a7, b0,b1,b2,b3,b4,b5,b6,b7, m2_0, mx_1);
    STEPC(SS + 1, b0,b1,b2,b3,b4,b5,b6,b7, a0,a1,a2,a3,a4,a5,a6,a7, m2_1, mx_0);
  }

  float accN = accN4.x + accN4.y + accN4.z + accN4.w;
  float accD = accD4.x + accD4.y + accD4.z + accD4.w;
  #pragma unroll
  for (int off = 32; off > 0; off >>= 1) {
    accN += __shfl_down(accN, off);
    accD += __shfl_down(accD, off);
  }
  if (lane == 0) { red[0][wid] = accN; red[1][wid] = accD; }
  __syncthreads();
  if (tid == 0) {
    float n  = red[0][0] + red[0][1] + red[0][2] + red[0][3];
    float dn = red[1][0] + red[1][1] + red[1][2] + red[1][3];
    atomicAdd(&acc[v * 2 + 0], (double)n);
    atomicAdd(&acc[v * 2 + 1], (double)dn);
  }
}

__global__ void finalize_kernel(const double* __restrict__ acc,
                                float* __restrict__ out)
{
  const double smooth = 1e-5;
  double cl[2];
  for (int b = 0; b < 2; ++b) {
    double tprec = acc[(0 * 2 + b) * 2 + 0] / (acc[(0 * 2 + b) * 2 + 1] + smooth);
    double tsens = acc[(1 * 2 + b) * 2 + 0] / (acc[(1 * 2 + b) * 2 + 1] + smooth);
    cl[b] = 2.0 * tprec * tsens / (tprec + tsens + smooth);
  }
  out[0] = (float)(1.0 - 0.5 * (cl[0] + cl[1]));
}

extern "C" void kernel_launch(void* const* d_in, const int* in_sizes, int n_in,
                              void* d_out, int out_size, void* d_ws, size_t ws_size,
                              hipStream_t stream) {
  const float* y_pred = (const float*)d_in[0];
  const float* y_true = (const float*)d_in[1];
  double* acc = (double*)d_ws;
  hipMemsetAsync(d_ws, 0, 8 * sizeof(double), stream);
  // 2048 waves: 4 role-vols x 8 d-chunks x 64 h-tiles -> 512 blocks x 4 waves
  skel_reduce_kernel<<<dim3(NWG), dim3(NT), 0, stream>>>(y_pred, y_true, acc);
  finalize_kernel<<<dim3(1), dim3(1), 0, stream>>>(acc, (float*)d_out);
}

// Round 10
// 74.837 us; speedup vs baseline: 4.8902x; 1.0086x over previous
//
#include <hip/hip_runtime.h>
#include <math.h>

#define DD 128
#define HH 256
#define WD 256
#define HWS (HH*WD)
#define VOLS ((size_t)DD*HWS)
#define DC 16          // slices per wave-tile -> 8 d-chunks (R5 best)
#define NT 256
#define NWG 512        // blocks; %8==0 for bijective XCD swizzle
#define FINF (__builtin_inff())

__device__ __forceinline__ float min3f(float a, float b, float c) {
  return fminf(fminf(a, b), c);   // fuses to v_min3_f32
}
__device__ __forceinline__ float max3f(float a, float b, float c) {
  return fmaxf(fmaxf(a, b), c);   // fuses to v_max3_f32
}

#define MIN3V(d,a,b,c) do{ (d).x=min3f((a).x,(b).x,(c).x); (d).y=min3f((a).y,(b).y,(c).y); \
                           (d).z=min3f((a).z,(b).z,(c).z); (d).w=min3f((a).w,(b).w,(c).w);}while(0)
#define MAX3V(d,a,b,c) do{ (d).x=max3f((a).x,(b).x,(c).x); (d).y=max3f((a).y,(b).y,(c).y); \
                           (d).z=max3f((a).z,(b).z,(c).z); (d).w=max3f((a).w,(b).w,(c).w);}while(0)
#define SET4(d,val)    do{ (d).x=(val); (d).y=(val); (d).z=(val); (d).w=(val);}while(0)

// One step, W-OUTERMOST ordering (fewer shuffles: 12 er W-min + 8 out W-max
// = 20/step vs 28 in the W-first form). Separable passes commute within
// erosion and within dilation, so: erode = minW(minD(minH)), dilate =
// maxW(maxH(maxD)) — W last on both sides puts shuffles only where needed.
// m2_0/m2_1 ping-pong holds H-min (hm) of the 2 previous slices;
// mx_0/mx_1 holds masked W-MIN-complete erosion (ew) of the 2 previous.
// All macro locals z-prefixed (R4 lesson: no self-init shadowing).
#define STEPW(SARG, M2WR, MXWR) do {                                          \
    const int  zS    = (SARG);                                                \
    const bool zsOK  = (zS >= 0 && zS < DD);                                  \
    const bool zeOK  = (zS >= 1 && zS <= DD);   /* er slice e=zS-1 in-volume */\
    const int  zo    = zS - 2;                                                \
    const bool zoOut = (zS >= d0 + 2);                                        \
    /* ---- stage loads first (consumed first; younger ic/ot stay in flight  \
       under the counted vmcnt wait) ---- */                                  \
    float4 vr[8];                                                             \
    if (zsOK) {                                                               \
      const float* zsb = imgL + (size_t)zS * HWS;                             \
      if (hOK0) vr[0] = *(const float4*)(zsb - 2*WD); else SET4(vr[0], FINF); \
      if (hOK1) vr[1] = *(const float4*)(zsb - 1*WD); else SET4(vr[1], FINF); \
      vr[2] = *(const float4*)(zsb);                                          \
      vr[3] = *(const float4*)(zsb + 1*WD);                                   \
      vr[4] = *(const float4*)(zsb + 2*WD);                                   \
      vr[5] = *(const float4*)(zsb + 3*WD);                                   \
      if (hOK6) vr[6] = *(const float4*)(zsb + 4*WD); else SET4(vr[6], FINF); \
      if (hOK7) vr[7] = *(const float4*)(zsb + 5*WD); else SET4(vr[7], FINF); \
    } else {                                                                  \
      _Pragma("unroll") for (int zr = 0; zr < 8; ++zr) SET4(vr[zr], FINF);    \
    }                                                                         \
    float4 ic[4], ot[4];                                                      \
    if (zoOut) {                                                              \
      const float* zib = imgL + (size_t)zo * HWS;                             \
      const float* zob = othL + (size_t)zo * HWS;                             \
      _Pragma("unroll") for (int zr = 0; zr < 4; ++zr) {                      \
        ic[zr] = *(const float4*)(zib + zr*WD);                               \
        ot[zr] = *(const float4*)(zob + zr*WD);                               \
      }                                                                       \
    }                                                                         \
    /* ---- H-min (pure VALU, 6 independent chains) ---- */                   \
    float4 hm[6], er[6];                                                      \
    _Pragma("unroll") for (int ri = 0; ri < 6; ++ri)                          \
      MIN3V(hm[ri], vr[ri], vr[ri+1], vr[ri+2]);                              \
    /* ---- D-min via ping-pong; read old state then overwrite ---- */        \
    _Pragma("unroll") for (int ri = 0; ri < 6; ++ri) {                        \
      MIN3V(er[ri], hm[ri], m2_0[ri], m2_1[ri]);                              \
      M2WR[ri] = hm[ri];                                                      \
    }                                                                         \
    /* ---- W-min (2 shuffles x 6 rows), dilation mask, D-max ---- */         \
    float4 qd[6];                                                             \
    _Pragma("unroll") for (int ri = 0; ri < 6; ++ri) {                        \
      float zlw = __shfl_up(er[ri].w, 1);   zlw = (lane == 0)  ? FINF : zlw;  \
      float zrx = __shfl_down(er[ri].x, 1); zrx = (lane == 63) ? FINF : zrx;  \
      float4 zew;                                                             \
      zew.x = min3f(zlw, er[ri].x, er[ri].y);                                 \
      zew.y = min3f(er[ri].x, er[ri].y, er[ri].z);                            \
      zew.z = min3f(er[ri].y, er[ri].z, er[ri].w);                            \
      zew.w = min3f(er[ri].z, er[ri].w, zrx);                                 \
      if (!(zeOK && ehOK[ri])) SET4(zew, -FINF);  /* outside-volume er */     \
      MAX3V(qd[ri], zew, mx_0[ri], mx_1[ri]);                                 \
      MXWR[ri] = zew;                                                         \
    }                                                                         \
    /* ---- H-max, W-max (2 shuffles x 4 rows), skel, fused reduce ---- */    \
    if (zoOut) {                                                              \
      _Pragma("unroll") for (int zr = 0; zr < 4; ++zr) {                      \
        float4 zon; MAX3V(zon, qd[zr], qd[zr+1], qd[zr+2]);                   \
        float zel = __shfl_up(zon.w, 1);   zel = (lane == 0)  ? -FINF : zel;  \
        float zer = __shfl_down(zon.x, 1); zer = (lane == 63) ? -FINF : zer;  \
        float4 zop;                                                           \
        zop.x = max3f(zel, zon.x, zon.y);                                     \
        zop.y = max3f(zon.x, zon.y, zon.z);                                   \
        zop.z = max3f(zon.y, zon.z, zon.w);                                   \
        zop.w = max3f(zon.z, zon.w, zer);                                     \
        float4 zsk;                                                           \
        zsk.x = fmaxf(ic[zr].x - zop.x, 0.f);                                 \
        zsk.y = fmaxf(ic[zr].y - zop.y, 0.f);                                 \
        zsk.z = fmaxf(ic[zr].z - zop.z, 0.f);                                 \
        zsk.w = fmaxf(ic[zr].w - zop.w, 0.f);                                 \
        accN4.x += zsk.x * ot[zr].x; accN4.y += zsk.y * ot[zr].y;             \
        accN4.z += zsk.z * ot[zr].z; accN4.w += zsk.w * ot[zr].w;             \
        accD4.x += zsk.x; accD4.y += zsk.y;                                   \
        accD4.z += zsk.z; accD4.w += zsk.w;                                   \
      }                                                                       \
    }                                                                         \
  } while (0)

// No waves-per-eu hint (R6: the hint clamps VGPR and spills; R8: it doesn't
// raise residency either). Natural allocation; tripwire: VGPR must stay <=128.
__global__ __launch_bounds__(NT) void skel_reduce_kernel(
    const float* __restrict__ y_pred, const float* __restrict__ y_true,
    double* __restrict__ acc)
{
  __shared__ float red[2][4];

  const int tid  = threadIdx.x;
  const int wid  = tid >> 6;
  const int lane = tid & 63;
  // Bijective XCD swizzle (512 blocks, 8 XCDs, 64-block contiguous chunks;
  // each chunk stays within one volume) -> halo/ic/ot re-reads are L2-local.
  const int bidsw = (blockIdx.x & 7) * (NWG / 8) + (blockIdx.x >> 3);
  const int gwv  = bidsw * 4 + wid;          // 0..2047
  const int ht = gwv & 63;                   // 64 h-tiles of 4 rows
  const int dt = (gwv >> 6) & 7;             // 8 d-chunks of 16 slices
  const int v  = gwv >> 9;                   // role*2 + b (block-uniform)
  const int role = v >> 1, b = v & 1;

  const float* img = (role == 0 ? y_pred : y_true) + (size_t)b * VOLS;
  const float* oth = (role == 0 ? y_true : y_pred) + (size_t)b * VOLS;

  const int h0 = ht * 4, d0 = dt * DC;
  const float* imgL = img + (size_t)h0 * WD + 4 * lane;
  const float* othL = oth + (size_t)h0 * WD + 4 * lane;

  // h-border validity (wave-uniform)
  const bool hOK0 = (h0 - 2 >= 0), hOK1 = (h0 - 1 >= 0);
  const bool hOK6 = (h0 + 4 < HH), hOK7 = (h0 + 5 < HH);
  bool ehOK[6];
  #pragma unroll
  for (int i = 0; i < 6; ++i) ehOK[i] = ((unsigned)(h0 + i - 1) < HH);

  // Ping-pong D-state: m2_* = H-min(img) per slice parity; mx_* = masked
  // full erosion (W-min applied) per slice parity.
  float4 m2_0[6], m2_1[6], mx_0[6], mx_1[6];
  #pragma unroll
  for (int i = 0; i < 6; ++i) {
    SET4(m2_0[i], FINF);  SET4(m2_1[i], FINF);
    SET4(mx_0[i], -FINF); SET4(mx_1[i], -FINF);
  }
  float4 accN4, accD4; SET4(accN4, 0.f); SET4(accD4, 0.f);

  // d0 even -> slice parity is compile-time in the 2x-unrolled loop.
  for (int SS = d0 - 2; SS < d0 + DC + 2; SS += 2) {
    STEPW(SS,     m2_0, mx_1);
    STEPW(SS + 1, m2_1, mx_0);
  }

  float accN = accN4.x + accN4.y + accN4.z + accN4.w;
  float accD = accD4.x + accD4.y + accD4.z + accD4.w;
  #pragma unroll
  for (int off = 32; off > 0; off >>= 1) {
    accN += __shfl_down(accN, off);
    accD += __shfl_down(accD, off);
  }
  if (lane == 0) { red[0][wid] = accN; red[1][wid] = accD; }
  __syncthreads();
  if (tid == 0) {
    float n  = red[0][0] + red[0][1] + red[0][2] + red[0][3];
    float dn = red[1][0] + red[1][1] + red[1][2] + red[1][3];
    atomicAdd(&acc[v * 2 + 0], (double)n);
    atomicAdd(&acc[v * 2 + 1], (double)dn);
  }
}

__global__ void finalize_kernel(const double* __restrict__ acc,
                                float* __restrict__ out)
{
  const double smooth = 1e-5;
  double cl[2];
  for (int b = 0; b < 2; ++b) {
    double tprec = acc[(0 * 2 + b) * 2 + 0] / (acc[(0 * 2 + b) * 2 + 1] + smooth);
    double tsens = acc[(1 * 2 + b) * 2 + 0] / (acc[(1 * 2 + b) * 2 + 1] + smooth);
    cl[b] = 2.0 * tprec * tsens / (tprec + tsens + smooth);
  }
  out[0] = (float)(1.0 - 0.5 * (cl[0] + cl[1]));
}

extern "C" void kernel_launch(void* const* d_in, const int* in_sizes, int n_in,
                              void* d_out, int out_size, void* d_ws, size_t ws_size,
                              hipStream_t stream) {
  const float* y_pred = (const float*)d_in[0];
  const float* y_true = (const float*)d_in[1];
  double* acc = (double*)d_ws;
  hipMemsetAsync(d_ws, 0, 8 * sizeof(double), stream);
  // 2048 waves: 4 role-vols x 8 d-chunks x 64 h-tiles -> 512 blocks x 4 waves
  skel_reduce_kernel<<<dim3(NWG), dim3(NT), 0, stream>>>(y_pred, y_true, acc);
  finalize_kernel<<<dim3(1), dim3(1), 0, stream>>>(acc, (float*)d_out);
}

// Round 11
// 52.607 us; speedup vs baseline: 6.9566x; 1.4226x over previous
//
#include <hip/hip_runtime.h>
#include <math.h>

#define DD 128
#define HH 256
#define WD 256
#define HWS (HH*WD)
#define VOLS ((size_t)DD*HWS)
#define DC 16          // slices per wave-tile -> 8 d-chunks (R5 best)
#define NT 512         // 8 waves/block: residency-law discriminator (R11)
#define NWG 256        // 2048 waves total, same work split as R5/R10
#define FINF (__builtin_inff())

__device__ __forceinline__ float min3f(float a, float b, float c) {
  return fminf(fminf(a, b), c);   // fuses to v_min3_f32
}
__device__ __forceinline__ float max3f(float a, float b, float c) {
  return fmaxf(fmaxf(a, b), c);   // fuses to v_max3_f32
}

#define MIN3V(d,a,b,c) do{ (d).x=min3f((a).x,(b).x,(c).x); (d).y=min3f((a).y,(b).y,(c).y); \
                           (d).z=min3f((a).z,(b).z,(c).z); (d).w=min3f((a).w,(b).w,(c).w);}while(0)
#define MAX3V(d,a,b,c) do{ (d).x=max3f((a).x,(b).x,(c).x); (d).y=max3f((a).y,(b).y,(c).y); \
                           (d).z=max3f((a).z,(b).z,(c).z); (d).w=max3f((a).w,(b).w,(c).w);}while(0)
#define SET4(d,val)    do{ (d).x=(val); (d).y=(val); (d).z=(val); (d).w=(val);}while(0)

// One step, W-outermost ordering (20 shuffles/step). Identical to R10.
// All macro locals z-prefixed (R4 lesson: no self-init shadowing).
#define STEPW(SARG, M2WR, MXWR) do {                                          \
    const int  zS    = (SARG);                                                \
    const bool zsOK  = (zS >= 0 && zS < DD);                                  \
    const bool zeOK  = (zS >= 1 && zS <= DD);   /* er slice e=zS-1 in-volume */\
    const int  zo    = zS - 2;                                                \
    const bool zoOut = (zS >= d0 + 2);                                        \
    float4 vr[8];                                                             \
    if (zsOK) {                                                               \
      const float* zsb = imgL + (size_t)zS * HWS;                             \
      if (hOK0) vr[0] = *(const float4*)(zsb - 2*WD); else SET4(vr[0], FINF); \
      if (hOK1) vr[1] = *(const float4*)(zsb - 1*WD); else SET4(vr[1], FINF); \
      vr[2] = *(const float4*)(zsb);                                          \
      vr[3] = *(const float4*)(zsb + 1*WD);                                   \
      vr[4] = *(const float4*)(zsb + 2*WD);                                   \
      vr[5] = *(const float4*)(zsb + 3*WD);                                   \
      if (hOK6) vr[6] = *(const float4*)(zsb + 4*WD); else SET4(vr[6], FINF); \
      if (hOK7) vr[7] = *(const float4*)(zsb + 5*WD); else SET4(vr[7], FINF); \
    } else {                                                                  \
      _Pragma("unroll") for (int zr = 0; zr < 8; ++zr) SET4(vr[zr], FINF);    \
    }                                                                         \
    float4 ic[4], ot[4];                                                      \
    if (zoOut) {                                                              \
      const float* zib = imgL + (size_t)zo * HWS;                             \
      const float* zob = othL + (size_t)zo * HWS;                             \
      _Pragma("unroll") for (int zr = 0; zr < 4; ++zr) {                      \
        ic[zr] = *(const float4*)(zib + zr*WD);                               \
        ot[zr] = *(const float4*)(zob + zr*WD);                               \
      }                                                                       \
    }                                                                         \
    /* H-min (pure VALU, 6 independent chains) */                             \
    float4 hm[6], er[6];                                                      \
    _Pragma("unroll") for (int ri = 0; ri < 6; ++ri)                          \
      MIN3V(hm[ri], vr[ri], vr[ri+1], vr[ri+2]);                              \
    /* D-min via ping-pong; read old state then overwrite */                  \
    _Pragma("unroll") for (int ri = 0; ri < 6; ++ri) {                        \
      MIN3V(er[ri], hm[ri], m2_0[ri], m2_1[ri]);                              \
      M2WR[ri] = hm[ri];                                                      \
    }                                                                         \
    /* W-min (2 shuffles x 6 rows), dilation mask, D-max */                   \
    float4 qd[6];                                                             \
    _Pragma("unroll") for (int ri = 0; ri < 6; ++ri) {                        \
      float zlw = __shfl_up(er[ri].w, 1);   zlw = (lane == 0)  ? FINF : zlw;  \
      float zrx = __shfl_down(er[ri].x, 1); zrx = (lane == 63) ? FINF : zrx;  \
      float4 zew;                                                             \
      zew.x = min3f(zlw, er[ri].x, er[ri].y);                                 \
      zew.y = min3f(er[ri].x, er[ri].y, er[ri].z);                            \
      zew.z = min3f(er[ri].y, er[ri].z, er[ri].w);                            \
      zew.w = min3f(er[ri].z, er[ri].w, zrx);                                 \
      if (!(zeOK && ehOK[ri])) SET4(zew, -FINF);  /* outside-volume er */     \
      MAX3V(qd[ri], zew, mx_0[ri], mx_1[ri]);                                 \
      MXWR[ri] = zew;                                                         \
    }                                                                         \
    /* H-max, W-max (2 shuffles x 4 rows), skel, fused reduce */              \
    if (zoOut) {                                                              \
      _Pragma("unroll") for (int zr = 0; zr < 4; ++zr) {                      \
        float4 zon; MAX3V(zon, qd[zr], qd[zr+1], qd[zr+2]);                   \
        float zel = __shfl_up(zon.w, 1);   zel = (lane == 0)  ? -FINF : zel;  \
        float zer = __shfl_down(zon.x, 1); zer = (lane == 63) ? -FINF : zer;  \
        float4 zop;                                                           \
        zop.x = max3f(zel, zon.x, zon.y);                                     \
        zop.y = max3f(zon.x, zon.y, zon.z);                                   \
        zop.z = max3f(zon.y, zon.z, zon.w);                                   \
        zop.w = max3f(zon.z, zon.w, zer);                                     \
        float4 zsk;                                                           \
        zsk.x = fmaxf(ic[zr].x - zop.x, 0.f);                                 \
        zsk.y = fmaxf(ic[zr].y - zop.y, 0.f);                                 \
        zsk.z = fmaxf(ic[zr].z - zop.z, 0.f);                                 \
        zsk.w = fmaxf(ic[zr].w - zop.w, 0.f);                                 \
        accN4.x += zsk.x * ot[zr].x; accN4.y += zsk.y * ot[zr].y;             \
        accN4.z += zsk.z * ot[zr].z; accN4.w += zsk.w * ot[zr].w;             \
        accD4.x += zsk.x; accD4.y += zsk.y;                                   \
        accD4.z += zsk.z; accD4.w += zsk.w;                                   \
      }                                                                       \
    }                                                                         \
  } while (0)

// No waves-per-eu hint (R6: clamps VGPR and spills; R8: doesn't raise
// residency). No XCD swizzle: at DC=16 it spread each XCD across 4 d-chunks
// and raised FETCH 147->205 MB (R5 vs R10); natural block order is
// slice-contiguous (blocks 0..7 = ht 0..63 of one dt).
__global__ __launch_bounds__(NT) void skel_reduce_kernel(
    const float* __restrict__ y_pred, const float* __restrict__ y_true,
    double* __restrict__ acc)
{
  __shared__ float red[2][8];

  const int tid  = threadIdx.x;
  const int wid  = tid >> 6;                 // 0..7
  const int lane = tid & 63;
  const int gwv  = blockIdx.x * 8 + wid;     // 0..2047
  const int ht = gwv & 63;                   // 64 h-tiles of 4 rows
  const int dt = (gwv >> 6) & 7;             // 8 d-chunks of 16 slices
  const int v  = gwv >> 9;                   // role*2 + b (block-uniform:
                                             // 512 waves = 64 blocks per v)
  const int role = v >> 1, b = v & 1;

  const float* img = (role == 0 ? y_pred : y_true) + (size_t)b * VOLS;
  const float* oth = (role == 0 ? y_true : y_pred) + (size_t)b * VOLS;

  const int h0 = ht * 4, d0 = dt * DC;
  const float* imgL = img + (size_t)h0 * WD + 4 * lane;
  const float* othL = oth + (size_t)h0 * WD + 4 * lane;

  // h-border validity (wave-uniform)
  const bool hOK0 = (h0 - 2 >= 0), hOK1 = (h0 - 1 >= 0);
  const bool hOK6 = (h0 + 4 < HH), hOK7 = (h0 + 5 < HH);
  bool ehOK[6];
  #pragma unroll
  for (int i = 0; i < 6; ++i) ehOK[i] = ((unsigned)(h0 + i - 1) < HH);

  // Ping-pong D-state: m2_* = H-min(img) per slice parity; mx_* = masked
  // full erosion (W-min applied) per slice parity.
  float4 m2_0[6], m2_1[6], mx_0[6], mx_1[6];
  #pragma unroll
  for (int i = 0; i < 6; ++i) {
    SET4(m2_0[i], FINF);  SET4(m2_1[i], FINF);
    SET4(mx_0[i], -FINF); SET4(mx_1[i], -FINF);
  }
  float4 accN4, accD4; SET4(accN4, 0.f); SET4(accD4, 0.f);

  // d0 even -> slice parity is compile-time in the 2x-unrolled loop.
  for (int SS = d0 - 2; SS < d0 + DC + 2; SS += 2) {
    STEPW(SS,     m2_0, mx_1);
    STEPW(SS + 1, m2_1, mx_0);
  }

  float accN = accN4.x + accN4.y + accN4.z + accN4.w;
  float accD = accD4.x + accD4.y + accD4.z + accD4.w;
  #pragma unroll
  for (int off = 32; off > 0; off >>= 1) {
    accN += __shfl_down(accN, off);
    accD += __shfl_down(accD, off);
  }
  if (lane == 0) { red[0][wid] = accN; red[1][wid] = accD; }
  __syncthreads();
  if (tid == 0) {
    float n = 0.f, dn = 0.f;
    #pragma unroll
    for (int w = 0; w < 8; ++w) { n += red[0][w]; dn += red[1][w]; }
    atomicAdd(&acc[v * 2 + 0], (double)n);
    atomicAdd(&acc[v * 2 + 1], (double)dn);
  }
}

__global__ void finalize_kernel(const double* __restrict__ acc,
                                float* __restrict__ out)
{
  const double smooth = 1e-5;
  double cl[2];
  for (int b = 0; b < 2; ++b) {
    double tprec = acc[(0 * 2 + b) * 2 + 0] / (acc[(0 * 2 + b) * 2 + 1] + smooth);
    double tsens = acc[(1 * 2 + b) * 2 + 0] / (acc[(1 * 2 + b) * 2 + 1] + smooth);
    cl[b] = 2.0 * tprec * tsens / (tprec + tsens + smooth);
  }
  out[0] = (float)(1.0 - 0.5 * (cl[0] + cl[1]));
}

extern "C" void kernel_launch(void* const* d_in, const int* in_sizes, int n_in,
                              void* d_out, int out_size, void* d_ws, size_t ws_size,
                              hipStream_t stream) {
  const float* y_pred = (const float*)d_in[0];
  const float* y_true = (const float*)d_in[1];
  double* acc = (double*)d_ws;
  hipMemsetAsync(d_ws, 0, 8 * sizeof(double), stream);
  // 2048 waves: 4 role-vols x 8 d-chunks x 64 h-tiles -> 256 blocks x 8 waves
  skel_reduce_kernel<<<dim3(NWG), dim3(NT), 0, stream>>>(y_pred, y_true, acc);
  finalize_kernel<<<dim3(1), dim3(1), 0, stream>>>(acc, (float*)d_out);
}